// Round 1
// baseline (260.839 us; speedup 1.0000x reference)
//
#include <hip/hip_runtime.h>

// Sparse 2-hop GCN slice: output depends only on h2[tgt], tgt = argmax(mut_mask).
// deg needs a full edge scan; neighborhood extraction needs a second scan.
// Everything else is ~300 small matvecs + a 1-block MLP head.

#define SCAP   512      // cap on |S1| (1-hop in-neighborhood of tgt); expected ~17
#define L1CAP  512      // cap on edges into tgt (incl. self loop); expected ~17
#define L2CAP  16384    // cap on edges into S1 nodes; expected ~300
#define HID    256
#define INDIM  128

struct WsPtrs {
  unsigned long long* key;  // packed argmax (floatbits<<32 | (0xFFFFFFFF - idx))
  int* cnt;                 // [0]=cntL1 [1]=cntS1 [2]=cntL2 [3]=is_int64_layout
  float* deg;               // [N]  (init 1.0 = self-loop weight)
  int* slot;                // [N]  node -> S1 slot, -1 = not member
  int* s1;                  // [SCAP] slot -> node
  int* l1r; float* l1w;     // layer-2 edge list (row, ew), col == tgt
  int* l2r; int* l2s; float* l2w; // layer-1 edge list (row, col-slot, ew)
  float* h1;                // [SCAP*HID] pre-activation accumulators
  float* h2;                // [HID]
};

__device__ __forceinline__ int ws_tgt(const WsPtrs& w) {
  unsigned long long k = *w.key;
  return (int)(0xFFFFFFFFu - (unsigned)(k & 0xFFFFFFFFull));
}

__global__ void kinit(WsPtrs w, const int* eiraw, int N) {
  int i = blockIdx.x * blockDim.x + threadIdx.x;
  int lim = SCAP * HID > N ? SCAP * HID : N;
  int stride = gridDim.x * blockDim.x;
  for (int j = i; j < lim; j += stride) {
    if (j < SCAP * HID) w.h1[j] = 0.f;
    if (j < HID)        w.h2[j] = 0.f;
    if (j < N)          { w.deg[j] = 1.0f; w.slot[j] = -1; }
  }
  if (i == 0) {
    *w.key = 0xFFFFFFFFull;               // (value 0.0, idx 0) sentinel
    w.cnt[0] = 0; w.cnt[1] = 0; w.cnt[2] = 0;
    // Detect whether edge_index is int64 (every odd int32 word == 0, since ids < 2^31)
    int is64 = 1;
    for (int j = 1; j <= 16; ++j) {
      if (eiraw[2 * (j * 1000) + 1] != 0) { is64 = 0; break; }
    }
    w.cnt[3] = is64;
  }
}

__global__ void kargmax(WsPtrs w, const float* mask, int N) {
  int i = blockIdx.x * blockDim.x + threadIdx.x;
  int stride = gridDim.x * blockDim.x;
  for (int j = i; j < N; j += stride) {
    float m = mask[j];
    if (m > 0.f) {
      unsigned long long kk = ((unsigned long long)__float_as_uint(m) << 32)
                            | (unsigned long long)(0xFFFFFFFFu - (unsigned)j);
      atomicMax(w.key, kk);
    }
  }
}

__device__ __forceinline__ void reg_s1(WsPtrs& w, int r) {
  int old = atomicCAS(&w.slot[r], -1, -2);
  if (old == -1) {
    int idx = atomicAdd(&w.cnt[1], 1);
    if (idx < SCAP) { w.s1[idx] = r; w.slot[r] = idx; }
  }
}

__global__ void kpass1(WsPtrs w, const int* eiraw, const float* ew, int E) {
  int tgt = ws_tgt(w);
  bool is64 = w.cnt[3] != 0;
  int i = blockIdx.x * blockDim.x + threadIdx.x;
  int stride = gridDim.x * blockDim.x;
  for (int e = i; e < E; e += stride) {
    int c = is64 ? eiraw[2 * ((long)E + e)] : eiraw[(long)E + e];
    float wt = ew[e];
    atomicAdd(&w.deg[c], wt);
    if (c == tgt) {
      int r = is64 ? eiraw[2 * (long)e] : eiraw[e];
      int i1 = atomicAdd(&w.cnt[0], 1);
      if (i1 < L1CAP) { w.l1r[i1] = r; w.l1w[i1] = wt; }
      reg_s1(w, r);
    }
  }
  if (i == 0) {  // tgt's self loop (weight 1.0)
    int i1 = atomicAdd(&w.cnt[0], 1);
    if (i1 < L1CAP) { w.l1r[i1] = tgt; w.l1w[i1] = 1.0f; }
    reg_s1(w, tgt);
  }
}

__global__ void kpass2(WsPtrs w, const int* eiraw, const float* ew, int E) {
  bool is64 = w.cnt[3] != 0;
  int i = blockIdx.x * blockDim.x + threadIdx.x;
  int stride = gridDim.x * blockDim.x;
  int ns = w.cnt[1]; if (ns > SCAP) ns = SCAP;
  for (int j = i; j < ns; j += stride) {  // self loops for S1 nodes
    int idx = atomicAdd(&w.cnt[2], 1);
    if (idx < L2CAP) { w.l2r[idx] = w.s1[j]; w.l2s[idx] = j; w.l2w[idx] = 1.0f; }
  }
  for (int e = i; e < E; e += stride) {
    int c = is64 ? eiraw[2 * ((long)E + e)] : eiraw[(long)E + e];
    int s = w.slot[c];
    if (s >= 0) {
      int r = is64 ? eiraw[2 * (long)e] : eiraw[e];
      int idx = atomicAdd(&w.cnt[2], 1);
      if (idx < L2CAP) { w.l2r[idx] = r; w.l2s[idx] = s; w.l2w[idx] = ew[e]; }
    }
  }
}

// One block (256 thr) per layer-1 edge: h1[s] += norm * (x[r] @ W1)
__global__ void kh1(WsPtrs w, const float* x, const float* W1) {
  __shared__ float xs[INDIM];
  int n = w.cnt[2]; if (n > L2CAP) n = L2CAP;
  int tid = threadIdx.x;
  for (int b = blockIdx.x; b < n; b += gridDim.x) {
    int r = w.l2r[b], s = w.l2s[b];
    float wt = w.l2w[b];
    int c = w.s1[s];
    float norm = rsqrtf(w.deg[r]) * wt * rsqrtf(w.deg[c]);
    if (tid < INDIM) xs[tid] = x[(long)r * INDIM + tid];
    __syncthreads();
    float acc = 0.f;
    #pragma unroll 8
    for (int k = 0; k < INDIM; ++k) acc += xs[k] * W1[k * HID + tid];
    atomicAdd(&w.h1[s * HID + tid], norm * acc);
    __syncthreads();
  }
}

// One block (256 thr) per layer-2 edge: h2 += norm * (relu(h1[slot[v]]+b1) @ W2)
__global__ void kh2(WsPtrs w, const float* W2, const float* b1) {
  __shared__ float hs[HID];
  int n = w.cnt[0]; if (n > L1CAP) n = L1CAP;
  int tid = threadIdx.x;
  int tgt = ws_tgt(w);
  float dti = rsqrtf(w.deg[tgt]);
  for (int b = blockIdx.x; b < n; b += gridDim.x) {
    int v = w.l1r[b]; float wt = w.l1w[b];
    int s = w.slot[v];
    hs[tid] = (s >= 0) ? fmaxf(w.h1[s * HID + tid] + b1[tid], 0.f) : 0.f;
    __syncthreads();
    float norm = rsqrtf(w.deg[v]) * wt * dti;
    float acc = 0.f;
    #pragma unroll 8
    for (int k = 0; k < HID; ++k) acc += hs[k] * W2[k * HID + tid];
    atomicAdd(&w.h2[tid], norm * acc);
    __syncthreads();
  }
}

// Single block, 512 threads: feature assembly + 3-layer MLP head
__global__ void khead(WsPtrs w, const float* b2, const float* mask,
                      const int* wtI_, const int* mutI_,
                      const float* aa, const float* pemb,
                      const float* Wh1, const float* bh1,
                      const float* Wh2, const float* bh2,
                      const float* Wh3, const float* bh3,
                      float* out) {
  __shared__ float feat[480];
  __shared__ float f1[512];
  __shared__ float f2[128];
  int tid = threadIdx.x;
  int tgt = ws_tgt(w);
  if (tid < HID) feat[tid] = fmaxf(w.h2[tid] + b2[tid], 0.f) * mask[tgt];
  int wtI = wtI_[0], mutI = mutI_[0];   // small non-negative: low word works for i32 or i64
  if (tid < 64) {
    float a = aa[wtI * 64 + tid];
    float b = aa[mutI * 64 + tid];
    feat[256 + tid] = a;        // wt
    feat[320 + tid] = b;        // mut
    feat[384 + tid] = b - a;    // delta
  }
  int pos = tgt; if (pos > 511) pos = 511; if (pos < 0) pos = 0;
  if (tid < 32) feat[448 + tid] = pemb[pos * 32 + tid];
  __syncthreads();
  float v1 = bh1[tid];
  for (int k = 0; k < 480; ++k) v1 += feat[k] * Wh1[k * 512 + tid];
  f1[tid] = fmaxf(v1, 0.f);
  __syncthreads();
  if (tid < 128) {
    float v2 = bh2[tid];
    for (int k = 0; k < 512; ++k) v2 += f1[k] * Wh2[k * 128 + tid];
    f2[tid] = fmaxf(v2, 0.f) * Wh3[tid];
  }
  __syncthreads();
  if (tid == 0) {
    float s = bh3[0];
    for (int k = 0; k < 128; ++k) s += f2[k];
    out[0] = s;
  }
}

extern "C" void kernel_launch(void* const* d_in, const int* in_sizes, int n_in,
                              void* d_out, int out_size, void* d_ws, size_t ws_size,
                              hipStream_t stream) {
  const float* x    = (const float*)d_in[0];
  const int*   ei   = (const int*)d_in[1];
  const float* ew   = (const float*)d_in[2];
  const float* mask = (const float*)d_in[3];
  const int*   wtI  = (const int*)d_in[4];
  const int*   mutI = (const int*)d_in[5];
  const float* W1   = (const float*)d_in[6];
  const float* b1   = (const float*)d_in[7];
  const float* W2   = (const float*)d_in[8];
  const float* b2   = (const float*)d_in[9];
  const float* aa   = (const float*)d_in[10];
  const float* pemb = (const float*)d_in[11];
  const float* Wh1  = (const float*)d_in[12];
  const float* bh1  = (const float*)d_in[13];
  const float* Wh2  = (const float*)d_in[14];
  const float* bh2  = (const float*)d_in[15];
  const float* Wh3  = (const float*)d_in[16];
  const float* bh3  = (const float*)d_in[17];
  float* out = (float*)d_out;
  const int N = in_sizes[3];   // mut_mask length
  const int E = in_sizes[2];   // edge_weight length

  char* p = (char*)d_ws;
  auto take = [&](size_t bytes) -> char* {
    char* q = p; p += (bytes + 255) & ~(size_t)255; return q;
  };
  WsPtrs w;
  w.key  = (unsigned long long*)take(8);
  w.cnt  = (int*)take(16);
  w.deg  = (float*)take((size_t)N * 4);
  w.slot = (int*)take((size_t)N * 4);
  w.s1   = (int*)take(SCAP * 4);
  w.l1r  = (int*)take(L1CAP * 4);
  w.l1w  = (float*)take(L1CAP * 4);
  w.l2r  = (int*)take(L2CAP * 4);
  w.l2s  = (int*)take(L2CAP * 4);
  w.l2w  = (float*)take(L2CAP * 4);
  w.h1   = (float*)take((size_t)SCAP * HID * 4);
  w.h2   = (float*)take(HID * 4);

  kinit  <<<512, 256, 0, stream>>>(w, ei, N);
  kargmax<<<256, 256, 0, stream>>>(w, mask, N);
  kpass1 <<<2048, 256, 0, stream>>>(w, ei, ew, E);
  kpass2 <<<2048, 256, 0, stream>>>(w, ei, ew, E);
  kh1    <<<512, 256, 0, stream>>>(w, x, W1);
  kh2    <<<64, 256, 0, stream>>>(w, W2, b1);
  khead  <<<1, 512, 0, stream>>>(w, b2, mask, wtI, mutI, aa, pemb,
                                 Wh1, bh1, Wh2, bh2, Wh3, bh3, out);
}

// Round 2
// 193.311 us; speedup vs baseline: 1.3493x; 1.3493x over previous
//
#include <hip/hip_runtime.h>

// Sparse 2-hop GCN slice: output depends only on h2[tgt], tgt = argmax(mut_mask).
// R2: deg is computed ONLY for needed nodes (~300) via a 3rd scan, killing the
// 1.6M-atomic storm that made R1's kpass1 write 50 MB to HBM.

#define SCAP   512      // cap on |S1| (1-hop in-neighborhood of tgt); expected ~17
#define L1CAP  512      // cap on edges into tgt (incl. self loop); expected ~17
#define L2CAP  16384    // cap on edges into S1 nodes; expected ~300
#define HID    256
#define INDIM  128

struct WsPtrs {
  unsigned long long* key;  // packed argmax (floatbits<<32 | (0xFFFFFFFF - idx))
  int* cnt;                 // [0]=cntL1 [1]=cntS1 [2]=cntL2 [3]=is_int64_layout
  float* deg;               // [N]  lazily initialized (only needed nodes)
  int* slot;                // [N]  -1 unknown, >=0 S1 slot, -3 needed-for-deg
  int* s1;                  // [SCAP] slot -> node
  int* l1r; float* l1w;     // layer-2 edge list (row, ew), col == tgt
  int* l2r; int* l2s; float* l2w; // layer-1 edge list (row, col-slot, ew)
  float* h1;                // [SCAP*HID] pre-activation accumulators
  float* h2;                // [HID]
};

__device__ __forceinline__ int ws_tgt(const WsPtrs& w) {
  unsigned long long k = *w.key;
  return (int)(0xFFFFFFFFu - (unsigned)(k & 0xFFFFFFFFull));
}

__device__ __forceinline__ int load_col(const int* eiraw, bool is64, long E, long e) {
  return is64 ? (int)((const long long*)eiraw)[E + e] : eiraw[E + e];
}
__device__ __forceinline__ int load_row(const int* eiraw, bool is64, long e) {
  return is64 ? (int)((const long long*)eiraw)[e] : eiraw[e];
}

__global__ void kinit(WsPtrs w, const int* eiraw, int N) {
  int i = blockIdx.x * blockDim.x + threadIdx.x;
  int lim = SCAP * HID > N ? SCAP * HID : N;
  int stride = gridDim.x * blockDim.x;
  for (int j = i; j < lim; j += stride) {
    if (j < SCAP * HID) w.h1[j] = 0.f;
    if (j < HID)        w.h2[j] = 0.f;
    if (j < N)          w.slot[j] = -1;
  }
  if (i == 0) {
    *w.key = 0xFFFFFFFFull;               // (value 0.0, idx 0) sentinel
    w.cnt[0] = 0; w.cnt[1] = 0; w.cnt[2] = 0;
    // Detect whether edge_index is int64 (odd int32 words all 0 since ids < 2^31)
    int is64 = 1;
    for (int j = 1; j <= 16; ++j) {
      if (eiraw[2 * (j * 1000) + 1] != 0) { is64 = 0; break; }
    }
    w.cnt[3] = is64;
  }
}

__global__ void kargmax(WsPtrs w, const float* mask, int N) {
  int i = blockIdx.x * blockDim.x + threadIdx.x;
  int stride = gridDim.x * blockDim.x;
  for (int j = i; j < N; j += stride) {
    float m = mask[j];
    if (m > 0.f) {
      unsigned long long kk = ((unsigned long long)__float_as_uint(m) << 32)
                            | (unsigned long long)(0xFFFFFFFFu - (unsigned)j);
      atomicMax(w.key, kk);
    }
  }
}

__device__ __forceinline__ void reg_s1(WsPtrs& w, int r) {
  int old = atomicCAS(&w.slot[r], -1, -2);
  if (old == -1) {
    w.deg[r] = 1.0f;                       // self-loop weight; lazily initialized
    int idx = atomicAdd(&w.cnt[1], 1);
    if (idx < SCAP) { w.s1[idx] = r; w.slot[r] = idx; }
    else            { w.slot[r] = -3; }    // overflow: still deg-tracked
  }
}

// passA: find edges into tgt; build S1
__global__ void kpassA(WsPtrs w, const int* eiraw, const float* ew, int E) {
  int tgt = ws_tgt(w);
  bool is64 = w.cnt[3] != 0;
  int i = blockIdx.x * blockDim.x + threadIdx.x;
  int stride = gridDim.x * blockDim.x;
  for (long e = i; e < E; e += stride) {
    int c = load_col(eiraw, is64, E, e);
    if (c == tgt) {
      int r = load_row(eiraw, is64, e);
      int i1 = atomicAdd(&w.cnt[0], 1);
      if (i1 < L1CAP) { w.l1r[i1] = r; w.l1w[i1] = ew[e]; }
      reg_s1(w, r);
    }
  }
  if (i == 0) {  // tgt's self loop (weight 1.0)
    int i1 = atomicAdd(&w.cnt[0], 1);
    if (i1 < L1CAP) { w.l1r[i1] = tgt; w.l1w[i1] = 1.0f; }
    reg_s1(w, tgt);
  }
}

// passB: find edges into S1; mark their rows as deg-needed
__global__ void kpassB(WsPtrs w, const int* eiraw, const float* ew, int E) {
  bool is64 = w.cnt[3] != 0;
  int i = blockIdx.x * blockDim.x + threadIdx.x;
  int stride = gridDim.x * blockDim.x;
  int ns = w.cnt[1]; if (ns > SCAP) ns = SCAP;
  for (int j = i; j < ns; j += stride) {  // self loops for S1 nodes
    int idx = atomicAdd(&w.cnt[2], 1);
    if (idx < L2CAP) { w.l2r[idx] = w.s1[j]; w.l2s[idx] = j; w.l2w[idx] = 1.0f; }
  }
  for (long e = i; e < E; e += stride) {
    int c = load_col(eiraw, is64, E, e);
    int s = w.slot[c];
    if (s >= 0) {
      int r = load_row(eiraw, is64, e);
      int idx = atomicAdd(&w.cnt[2], 1);
      if (idx < L2CAP) { w.l2r[idx] = r; w.l2s[idx] = s; w.l2w[idx] = ew[e]; }
      int old = atomicCAS(&w.slot[r], -1, -3);
      if (old == -1) w.deg[r] = 1.0f;
    }
  }
}

// passC: accumulate deg ONLY for marked nodes (~300) — ~5K atomics, not 1.6M
__global__ void kpassC(WsPtrs w, const int* eiraw, const float* ew, int E) {
  bool is64 = w.cnt[3] != 0;
  int i = blockIdx.x * blockDim.x + threadIdx.x;
  int stride = gridDim.x * blockDim.x;
  for (long e = i; e < E; e += stride) {
    int c = load_col(eiraw, is64, E, e);
    if (w.slot[c] != -1) atomicAdd(&w.deg[c], ew[e]);
  }
}

// One block (256 thr) per layer-1 edge: h1[s] += norm * (x[r] @ W1)
__global__ void kh1(WsPtrs w, const float* x, const float* W1) {
  __shared__ float xs[INDIM];
  int n = w.cnt[2]; if (n > L2CAP) n = L2CAP;
  int tid = threadIdx.x;
  for (int b = blockIdx.x; b < n; b += gridDim.x) {
    int r = w.l2r[b], s = w.l2s[b];
    float wt = w.l2w[b];
    int c = w.s1[s];
    float norm = rsqrtf(w.deg[r]) * wt * rsqrtf(w.deg[c]);
    if (tid < INDIM) xs[tid] = x[(long)r * INDIM + tid];
    __syncthreads();
    float acc = 0.f;
    #pragma unroll 8
    for (int k = 0; k < INDIM; ++k) acc += xs[k] * W1[k * HID + tid];
    atomicAdd(&w.h1[s * HID + tid], norm * acc);
    __syncthreads();
  }
}

// One block (256 thr) per layer-2 edge: h2 += norm * (relu(h1[slot[v]]+b1) @ W2)
__global__ void kh2(WsPtrs w, const float* W2, const float* b1) {
  __shared__ float hs[HID];
  int n = w.cnt[0]; if (n > L1CAP) n = L1CAP;
  int tid = threadIdx.x;
  int tgt = ws_tgt(w);
  float dti = rsqrtf(w.deg[tgt]);
  for (int b = blockIdx.x; b < n; b += gridDim.x) {
    int v = w.l1r[b]; float wt = w.l1w[b];
    int s = w.slot[v];
    hs[tid] = (s >= 0) ? fmaxf(w.h1[s * HID + tid] + b1[tid], 0.f) : 0.f;
    __syncthreads();
    float norm = rsqrtf(w.deg[v]) * wt * dti;
    float acc = 0.f;
    #pragma unroll 8
    for (int k = 0; k < HID; ++k) acc += hs[k] * W2[k * HID + tid];
    atomicAdd(&w.h2[tid], norm * acc);
    __syncthreads();
  }
}

// Single block, 512 threads: feature assembly + 3-layer MLP head
__global__ void khead(WsPtrs w, const float* b2, const float* mask,
                      const int* wtI_, const int* mutI_,
                      const float* aa, const float* pemb,
                      const float* Wh1, const float* bh1,
                      const float* Wh2, const float* bh2,
                      const float* Wh3, const float* bh3,
                      float* out) {
  __shared__ float feat[480];
  __shared__ float f1[512];
  __shared__ float f2[128];
  int tid = threadIdx.x;
  int tgt = ws_tgt(w);
  if (tid < HID) feat[tid] = fmaxf(w.h2[tid] + b2[tid], 0.f) * mask[tgt];
  int wtI = wtI_[0], mutI = mutI_[0];   // small non-negative: low word ok for i32/i64
  if (tid < 64) {
    float a = aa[wtI * 64 + tid];
    float b = aa[mutI * 64 + tid];
    feat[256 + tid] = a;        // wt
    feat[320 + tid] = b;        // mut
    feat[384 + tid] = b - a;    // delta
  }
  int pos = tgt; if (pos > 511) pos = 511; if (pos < 0) pos = 0;
  if (tid < 32) feat[448 + tid] = pemb[pos * 32 + tid];
  __syncthreads();
  float v1 = bh1[tid];
  for (int k = 0; k < 480; ++k) v1 += feat[k] * Wh1[k * 512 + tid];
  f1[tid] = fmaxf(v1, 0.f);
  __syncthreads();
  if (tid < 128) {
    float v2 = bh2[tid];
    for (int k = 0; k < 512; ++k) v2 += f1[k] * Wh2[k * 128 + tid];
    f2[tid] = fmaxf(v2, 0.f) * Wh3[tid];
  }
  __syncthreads();
  if (tid == 0) {
    float s = bh3[0];
    for (int k = 0; k < 128; ++k) s += f2[k];
    out[0] = s;
  }
}

extern "C" void kernel_launch(void* const* d_in, const int* in_sizes, int n_in,
                              void* d_out, int out_size, void* d_ws, size_t ws_size,
                              hipStream_t stream) {
  const float* x    = (const float*)d_in[0];
  const int*   ei   = (const int*)d_in[1];
  const float* ew   = (const float*)d_in[2];
  const float* mask = (const float*)d_in[3];
  const int*   wtI  = (const int*)d_in[4];
  const int*   mutI = (const int*)d_in[5];
  const float* W1   = (const float*)d_in[6];
  const float* b1   = (const float*)d_in[7];
  const float* W2   = (const float*)d_in[8];
  const float* b2   = (const float*)d_in[9];
  const float* aa   = (const float*)d_in[10];
  const float* pemb = (const float*)d_in[11];
  const float* Wh1  = (const float*)d_in[12];
  const float* bh1  = (const float*)d_in[13];
  const float* Wh2  = (const float*)d_in[14];
  const float* bh2  = (const float*)d_in[15];
  const float* Wh3  = (const float*)d_in[16];
  const float* bh3  = (const float*)d_in[17];
  float* out = (float*)d_out;
  const int N = in_sizes[3];   // mut_mask length
  const int E = in_sizes[2];   // edge_weight length

  char* p = (char*)d_ws;
  auto take = [&](size_t bytes) -> char* {
    char* q = p; p += (bytes + 255) & ~(size_t)255; return q;
  };
  WsPtrs w;
  w.key  = (unsigned long long*)take(8);
  w.cnt  = (int*)take(16);
  w.deg  = (float*)take((size_t)N * 4);
  w.slot = (int*)take((size_t)N * 4);
  w.s1   = (int*)take(SCAP * 4);
  w.l1r  = (int*)take(L1CAP * 4);
  w.l1w  = (float*)take(L1CAP * 4);
  w.l2r  = (int*)take(L2CAP * 4);
  w.l2s  = (int*)take(L2CAP * 4);
  w.l2w  = (float*)take(L2CAP * 4);
  w.h1   = (float*)take((size_t)SCAP * HID * 4);
  w.h2   = (float*)take(HID * 4);

  kinit  <<<512, 256, 0, stream>>>(w, ei, N);
  kargmax<<<256, 256, 0, stream>>>(w, mask, N);
  kpassA <<<2048, 256, 0, stream>>>(w, ei, ew, E);
  kpassB <<<2048, 256, 0, stream>>>(w, ei, ew, E);
  kpassC <<<2048, 256, 0, stream>>>(w, ei, ew, E);
  kh1    <<<512, 256, 0, stream>>>(w, x, W1);
  kh2    <<<64, 256, 0, stream>>>(w, W2, b1);
  khead  <<<1, 512, 0, stream>>>(w, b2, mask, wtI, mutI, aa, pemb,
                                 Wh1, bh1, Wh2, bh2, Wh3, bh3, out);
}